// Round 3
// baseline (1726.496 us; speedup 1.0000x reference)
//
#include <hip/hip_runtime.h>
#include <hip/hip_bf16.h>

#define NN 50000
#define EE 800000
#define INF 512
#define HH 8
#define DD 64
#define HD 512
#define NTOT 1024   // fused GEMM output cols: [ft | res]

typedef unsigned short u16;
typedef u16 u16x8 __attribute__((ext_vector_type(8)));
typedef __bf16 bf16x8 __attribute__((ext_vector_type(8)));
typedef float f32x4 __attribute__((ext_vector_type(4)));

__device__ __forceinline__ float bf2f(u16 u) {
    return __uint_as_float(((unsigned)u) << 16);
}
__device__ __forceinline__ u16 f2bf(float f) {
    __hip_bfloat16 h = __float2bfloat16(f);
    return *reinterpret_cast<u16*>(&h);
}

// -------- per-input dtype sniff: flags[i]=1 if input i is f32, 0 if bf16 --------
// bf16 inputs here are all |x| < ~6 -> every u16 decodes small -> bad=0.
// f32 inputs: even-indexed u16s are low mantissa bits -> ~45% decode |x|>1e4.
// Deterministic (inputs restored before every launch). One block per input.
__global__ __launch_bounds__(256) void sniff5_kernel(const u16* __restrict__ p0,
                                                     const u16* __restrict__ p1,
                                                     const u16* __restrict__ p2,
                                                     const u16* __restrict__ p3,
                                                     const u16* __restrict__ p4,
                                                     int* __restrict__ flags) {
    const u16* ps[5] = {p0, p1, p2, p3, p4};
    const u16* p = ps[blockIdx.x];
    __shared__ int bad;
    if (threadIdx.x == 0) bad = 0;
    __syncthreads();
    float v = fabsf(bf2f(p[2 * threadIdx.x]));
    if (!(v < 1e4f)) atomicAdd(&bad, 1);  // catches huge / inf / NaN
    __syncthreads();
    if (threadIdx.x == 0) flags[blockIdx.x] = (bad >= 8) ? 1 : 0;
}

// ---------------- W transpose (+ dtype convert): Wt[col][k] = W[k][col], 512x512 ----------------
__global__ __launch_bounds__(256) void transpose_kernel(const void* __restrict__ in,
                                                        u16* __restrict__ out,
                                                        const int* __restrict__ flag) {
    __shared__ u16 tile[64][65];
    const int isf32 = *flag;
    int tr = (blockIdx.x & 7) * 64;   // k tile
    int tc = (blockIdx.x >> 3) * 64;  // col tile
    for (int idx = threadIdx.x; idx < 64 * 64; idx += 256) {
        int r = idx >> 6, c = idx & 63;
        int g = (tr + r) * 512 + tc + c;
        tile[r][c] = isf32 ? f2bf(((const float*)in)[g]) : ((const u16*)in)[g];
    }
    __syncthreads();
    for (int idx = threadIdx.x; idx < 64 * 64; idx += 256) {
        int r = idx >> 6, c = idx & 63;
        out[(tc + r) * 512 + tr + c] = tile[c][r];
    }
}

// ---------------- init m (ordered-int -inf) and s (0) ----------------
__global__ void init_kernel(int* __restrict__ m_enc, float* __restrict__ s_sum) {
    int t = blockIdx.x * 256 + threadIdx.x;
    if (t < NN * HH) {
        m_enc[t] = (int)0x80000000;
        s_sum[t] = 0.0f;
    }
}

// ---- fused GEMM: [N,512] @ [512,1024] -> ft (bf16) | residual -> out (f32) ----
#define TM 128
#define TN 128
#define BK 32
#define LDK 40  // padded LDS k-stride (2-way bank aliasing only -> free)

__global__ __launch_bounds__(256) void gemm_kernel(const void* __restrict__ A,
                                                   const u16* __restrict__ Wt,
                                                   u16* __restrict__ ft,
                                                   float* __restrict__ outf,
                                                   const int* __restrict__ flag) {
    __shared__ u16 As[TM * LDK];
    __shared__ u16 Bs[TN * LDK];
    const int isf32 = *flag;
    const int m0 = blockIdx.x * TM;
    const int n0 = blockIdx.y * TN;
    const int tid = threadIdx.x;
    const int lane = tid & 63;
    const int wave = tid >> 6;
    const int wr = (wave >> 1) * 64;
    const int wc = (wave & 1) * 64;
    const int lrow = lane & 15;
    const int quad = lane >> 4;

    f32x4 acc[4][4] = {};

    for (int k0 = 0; k0 < INF; k0 += BK) {
        __syncthreads();
#pragma unroll
        for (int it = 0; it < 2; ++it) {
            int chunk = tid + it * 256;
            int r = chunk >> 2;
            int c = (chunk & 3) * 8;
            int gr = m0 + r;
            u16x8 av = {0, 0, 0, 0, 0, 0, 0, 0};
            if (gr < NN) {
                if (isf32) {
                    const float* ap = (const float*)A + gr * INF + k0 + c;
#pragma unroll
                    for (int j = 0; j < 8; ++j) av[j] = f2bf(ap[j]);
                } else {
                    av = *(const u16x8*)((const u16*)A + gr * INF + k0 + c);
                }
            }
            *(u16x8*)(As + r * LDK + c) = av;
            *(u16x8*)(Bs + r * LDK + c) = *(const u16x8*)(Wt + (n0 + r) * INF + k0 + c);
        }
        __syncthreads();

        bf16x8 af[4], bfr[4];
#pragma unroll
        for (int mi = 0; mi < 4; ++mi)
            af[mi] = *(const bf16x8*)(As + (wr + mi * 16 + lrow) * LDK + quad * 8);
#pragma unroll
        for (int ni = 0; ni < 4; ++ni)
            bfr[ni] = *(const bf16x8*)(Bs + (wc + ni * 16 + lrow) * LDK + quad * 8);
#pragma unroll
        for (int mi = 0; mi < 4; ++mi)
#pragma unroll
            for (int ni = 0; ni < 4; ++ni)
                acc[mi][ni] = __builtin_amdgcn_mfma_f32_16x16x32_bf16(af[mi], bfr[ni],
                                                                      acc[mi][ni], 0, 0, 0);
    }

    // epilogue: C layout col=lane&15, row=quad*4+reg (m89/m91-verified)
#pragma unroll
    for (int mi = 0; mi < 4; ++mi) {
        int rb = m0 + wr + mi * 16 + quad * 4;
#pragma unroll
        for (int ni = 0; ni < 4; ++ni) {
            int col = n0 + wc + ni * 16 + lrow;
#pragma unroll
            for (int r = 0; r < 4; ++r) {
                int row = rb + r;
                if (row < NN) {
                    float v = acc[mi][ni][r];
                    if (col < HD) ft[row * HD + col] = f2bf(v);
                    else outf[row * HD + (col - HD)] = v;  // residual init of d_out
                }
            }
        }
    }
}

// ---------------- el/er: per-node attention dots ----------------
__global__ __launch_bounds__(256) void attn_dot_kernel(const u16* __restrict__ ft,
                                                       const void* __restrict__ al,
                                                       const void* __restrict__ ar,
                                                       float* __restrict__ el,
                                                       float* __restrict__ er,
                                                       const int* __restrict__ flags) {
    int node = blockIdx.x * 4 + (threadIdx.x >> 6);
    int lane = threadIdx.x & 63;
    if (node >= NN) return;
    const int alf32 = flags[3];
    const int arf32 = flags[4];
    const u16* f = ft + node * HD;
#pragma unroll
    for (int h = 0; h < HH; ++h) {
        int i = h * 64 + lane;
        float wl = alf32 ? ((const float*)al)[i] : bf2f(((const u16*)al)[i]);
        float wr_ = arf32 ? ((const float*)ar)[i] : bf2f(((const u16*)ar)[i]);
        float x = bf2f(f[i]);
        float vl = x * wl;
        float vr = x * wr_;
#pragma unroll
        for (int off = 32; off > 0; off >>= 1) {
            vl += __shfl_down(vl, off);
            vr += __shfl_down(vr, off);
        }
        if (lane == 0) {
            el[node * HH + h] = vl;
            er[node * HH + h] = vr;
        }
    }
}

// ---------------- edge logits + segment max (ordered-int atomicMax) ----------------
__global__ void edge_logits_kernel(const int* __restrict__ src, const int* __restrict__ dst,
                                   const float* __restrict__ el, const float* __restrict__ er,
                                   float* __restrict__ e_ws, int* __restrict__ m_enc) {
    int t = blockIdx.x * 256 + threadIdx.x;
    if (t >= EE * HH) return;
    int e = t >> 3, h = t & 7;
    int s_ = src[e], d_ = dst[e];
    float v = el[s_ * HH + h] + er[d_ * HH + h];
    v = v > 0.0f ? v : 0.2f * v;  // LeakyReLU
    e_ws[t] = v;
    int enc = __float_as_int(v);
    enc = enc >= 0 ? enc : (enc ^ 0x7fffffff);
    atomicMax(&m_enc[d_ * HH + h], enc);
}

// ---------------- exp + segment sum ----------------
__global__ void edge_exp_kernel(const int* __restrict__ dst, float* __restrict__ e_ws,
                                const int* __restrict__ m_enc, float* __restrict__ s_sum) {
    int t = blockIdx.x * 256 + threadIdx.x;
    if (t >= EE * HH) return;
    int e = t >> 3, h = t & 7;
    int d_ = dst[e];
    int enc = m_enc[d_ * HH + h];
    float m = __int_as_float(enc >= 0 ? enc : (enc ^ 0x7fffffff));
    float ex = __expf(e_ws[t] - m);
    e_ws[t] = ex;  // in-place: now holds exp values
    unsafeAtomicAdd(&s_sum[d_ * HH + h], ex);
}

// ---------------- weighted message scatter-add into d_out: one wave per edge ----------------
__global__ __launch_bounds__(256) void aggregate_kernel(const int* __restrict__ src,
                                                        const int* __restrict__ dst,
                                                        const u16* __restrict__ ft,
                                                        const float* __restrict__ e_ws,
                                                        const float* __restrict__ s_sum,
                                                        float* __restrict__ outf) {
    int e = blockIdx.x * 4 + (threadIdx.x >> 6);
    if (e >= EE) return;
    int lane = threadIdx.x & 63;
    int s_ = src[e], d_ = dst[e];
    const u16* fs = ft + s_ * HD;
    float* ad = outf + d_ * HD;
#pragma unroll
    for (int h = 0; h < HH; ++h) {
        float sden = s_sum[d_ * HH + h];
        float w = e_ws[e * HH + h] / fmaxf(sden, 1e-9f);
        float x = bf2f(fs[h * 64 + lane]);
        unsafeAtomicAdd(&ad[h * 64 + lane], x * w);
    }
}

extern "C" void kernel_launch(void* const* d_in, const int* in_sizes, int n_in,
                              void* d_out, int out_size, void* d_ws, size_t ws_size,
                              hipStream_t stream) {
    const void* feat   = d_in[0];
    const int*  src    = (const int*)d_in[1];
    const int*  dst    = (const int*)d_in[2];
    const void* W_fc   = d_in[3];
    const void* W_res  = d_in[4];
    const void* attn_l = d_in[5];
    const void* attn_r = d_in[6];
    float* outf = (float*)d_out;

    char* ws = (char*)d_ws;
    int*   flags = (int*)(ws);                //        256 B (20 used) [feat,wfc,wres,al,ar]
    u16*   Wt    = (u16*)(ws + 256);          //  1,048,576 B  [1024][512] bf16
    u16*   ft    = (u16*)(ws + 1048832);      // 51,200,000 B  [N][512] bf16
    float* el    = (float*)(ws + 52248832);   //  1,600,000 B  [N][8]
    float* er    = (float*)(ws + 53848832);   //  1,600,000 B
    int*   m_enc = (int*)(ws + 55448832);     //  1,600,000 B
    float* s_sum = (float*)(ws + 57048832);   //  1,600,000 B
    float* e_ws  = (float*)(ws + 58648832);   // 25,600,000 B  [E][8]  (end ~84.2 MB)

    sniff5_kernel<<<5, 256, 0, stream>>>((const u16*)feat, (const u16*)W_fc,
                                         (const u16*)W_res, (const u16*)attn_l,
                                         (const u16*)attn_r, flags);
    transpose_kernel<<<64, 256, 0, stream>>>(W_fc, Wt, flags + 1);
    transpose_kernel<<<64, 256, 0, stream>>>(W_res, Wt + 512 * 512, flags + 2);
    init_kernel<<<(NN * HH + 255) / 256, 256, 0, stream>>>(m_enc, s_sum);

    dim3 gg((NN + TM - 1) / TM, NTOT / TN);
    gemm_kernel<<<gg, 256, 0, stream>>>(feat, Wt, ft, outf, flags + 0);

    attn_dot_kernel<<<NN / 4, 256, 0, stream>>>(ft, attn_l, attn_r, el, er, flags);
    edge_logits_kernel<<<(EE * HH) / 256, 256, 0, stream>>>(src, dst, el, er, e_ws, m_enc);
    edge_exp_kernel<<<(EE * HH) / 256, 256, 0, stream>>>(dst, e_ws, m_enc, s_sum);
    aggregate_kernel<<<EE / 4, 256, 0, stream>>>(src, dst, ft, e_ws, s_sum, outf);
}

// Round 4
// 769.063 us; speedup vs baseline: 2.2449x; 2.2449x over previous
//
#include <hip/hip_runtime.h>
#include <hip/hip_bf16.h>

#define NN 50000
#define EE 800000
#define INF 512
#define HH 8
#define DD 64
#define HD 512
#define NTOT 1024   // fused GEMM output cols: [ft | res]

typedef unsigned short u16;
typedef u16 u16x8 __attribute__((ext_vector_type(8)));
typedef __bf16 bf16x8 __attribute__((ext_vector_type(8)));
typedef float f32x4 __attribute__((ext_vector_type(4)));

__device__ __forceinline__ float bf2f(u16 u) {
    return __uint_as_float(((unsigned)u) << 16);
}
__device__ __forceinline__ u16 f2bf(float f) {
    __hip_bfloat16 h = __float2bfloat16(f);
    return *reinterpret_cast<u16*>(&h);
}

// -------- per-input dtype sniff: flags[i]=1 if input i is f32, 0 if bf16 --------
__global__ __launch_bounds__(256) void sniff5_kernel(const u16* __restrict__ p0,
                                                     const u16* __restrict__ p1,
                                                     const u16* __restrict__ p2,
                                                     const u16* __restrict__ p3,
                                                     const u16* __restrict__ p4,
                                                     int* __restrict__ flags) {
    const u16* ps[5] = {p0, p1, p2, p3, p4};
    const u16* p = ps[blockIdx.x];
    __shared__ int bad;
    if (threadIdx.x == 0) bad = 0;
    __syncthreads();
    float v = fabsf(bf2f(p[2 * threadIdx.x]));
    if (!(v < 1e4f)) atomicAdd(&bad, 1);  // catches huge / inf / NaN
    __syncthreads();
    if (threadIdx.x == 0) flags[blockIdx.x] = (bad >= 8) ? 1 : 0;
}

// ---------------- W transpose (+ dtype convert): Wt[col][k] = W[k][col], 512x512 ----------------
__global__ __launch_bounds__(256) void transpose_kernel(const void* __restrict__ in,
                                                        u16* __restrict__ out,
                                                        const int* __restrict__ flag) {
    __shared__ u16 tile[64][65];
    const int isf32 = *flag;
    int tr = (blockIdx.x & 7) * 64;   // k tile
    int tc = (blockIdx.x >> 3) * 64;  // col tile
    for (int idx = threadIdx.x; idx < 64 * 64; idx += 256) {
        int r = idx >> 6, c = idx & 63;
        int g = (tr + r) * 512 + tc + c;
        tile[r][c] = isf32 ? f2bf(((const float*)in)[g]) : ((const u16*)in)[g];
    }
    __syncthreads();
    for (int idx = threadIdx.x; idx < 64 * 64; idx += 256) {
        int r = idx >> 6, c = idx & 63;
        out[(tc + r) * 512 + tr + c] = tile[c][r];
    }
}

// ---------------- CSR build: deg zero -> count -> scan -> scatter ----------------
__global__ void zero_deg_kernel(int* __restrict__ deg) {
    int t = blockIdx.x * 256 + threadIdx.x;
    if (t < NN) deg[t] = 0;
}

__global__ void count_kernel(const int* __restrict__ dst, int* __restrict__ deg) {
    int e = blockIdx.x * 256 + threadIdx.x;
    if (e < EE) atomicAdd(&deg[dst[e]], 1);
}

#define SCAN_CH 49  // 1024 * 49 = 50176 >= NN
__global__ __launch_bounds__(1024) void scan_kernel(const int* __restrict__ deg,
                                                    int* __restrict__ rowptr,
                                                    int* __restrict__ cursor) {
    __shared__ int sums[1024];
    int t = threadIdx.x;
    int base = t * SCAN_CH;
    int s = 0;
    for (int k = 0; k < SCAN_CH; ++k) {
        int i = base + k;
        if (i < NN) s += deg[i];
    }
    sums[t] = s;
    __syncthreads();
    // Hillis-Steele inclusive scan
    for (int off = 1; off < 1024; off <<= 1) {
        int v = (t >= off) ? sums[t - off] : 0;
        __syncthreads();
        sums[t] += v;
        __syncthreads();
    }
    int run = (t == 0) ? 0 : sums[t - 1];
    for (int k = 0; k < SCAN_CH; ++k) {
        int i = base + k;
        if (i < NN) {
            rowptr[i] = run;
            cursor[i] = run;
            run += deg[i];
        }
    }
    if (t == 0) rowptr[NN] = EE;
}

__global__ void scatter_kernel(const int* __restrict__ src, const int* __restrict__ dst,
                               int* __restrict__ cursor, int* __restrict__ csr_src) {
    int e = blockIdx.x * 256 + threadIdx.x;
    if (e < EE) {
        int p = atomicAdd(&cursor[dst[e]], 1);
        csr_src[p] = src[e];
    }
}

// ---- fused GEMM: [N,512] @ [512,1024] -> ft (bf16) | residual -> out (f32) ----
#define TM 128
#define TN 128
#define BK 32
#define LDK 40  // padded LDS k-stride (2-way bank aliasing only -> free)

__global__ __launch_bounds__(256) void gemm_kernel(const void* __restrict__ A,
                                                   const u16* __restrict__ Wt,
                                                   u16* __restrict__ ft,
                                                   float* __restrict__ outf,
                                                   const int* __restrict__ flag) {
    __shared__ u16 As[TM * LDK];
    __shared__ u16 Bs[TN * LDK];
    const int isf32 = *flag;
    const int m0 = blockIdx.x * TM;
    const int n0 = blockIdx.y * TN;
    const int tid = threadIdx.x;
    const int lane = tid & 63;
    const int wave = tid >> 6;
    const int wr = (wave >> 1) * 64;
    const int wc = (wave & 1) * 64;
    const int lrow = lane & 15;
    const int quad = lane >> 4;

    f32x4 acc[4][4] = {};

    for (int k0 = 0; k0 < INF; k0 += BK) {
        __syncthreads();
#pragma unroll
        for (int it = 0; it < 2; ++it) {
            int chunk = tid + it * 256;
            int r = chunk >> 2;
            int c = (chunk & 3) * 8;
            int gr = m0 + r;
            u16x8 av = {0, 0, 0, 0, 0, 0, 0, 0};
            if (gr < NN) {
                if (isf32) {
                    const f32x4* ap = (const f32x4*)((const float*)A + gr * INF + k0 + c);
                    f32x4 f0 = ap[0], f1 = ap[1];
#pragma unroll
                    for (int j = 0; j < 4; ++j) { av[j] = f2bf(f0[j]); av[4 + j] = f2bf(f1[j]); }
                } else {
                    av = *(const u16x8*)((const u16*)A + gr * INF + k0 + c);
                }
            }
            *(u16x8*)(As + r * LDK + c) = av;
            *(u16x8*)(Bs + r * LDK + c) = *(const u16x8*)(Wt + (n0 + r) * INF + k0 + c);
        }
        __syncthreads();

        bf16x8 af[4], bfr[4];
#pragma unroll
        for (int mi = 0; mi < 4; ++mi)
            af[mi] = *(const bf16x8*)(As + (wr + mi * 16 + lrow) * LDK + quad * 8);
#pragma unroll
        for (int ni = 0; ni < 4; ++ni)
            bfr[ni] = *(const bf16x8*)(Bs + (wc + ni * 16 + lrow) * LDK + quad * 8);
#pragma unroll
        for (int mi = 0; mi < 4; ++mi)
#pragma unroll
            for (int ni = 0; ni < 4; ++ni)
                acc[mi][ni] = __builtin_amdgcn_mfma_f32_16x16x32_bf16(af[mi], bfr[ni],
                                                                      acc[mi][ni], 0, 0, 0);
    }

    // epilogue: C layout col=lane&15, row=quad*4+reg (m89/m91-verified)
#pragma unroll
    for (int mi = 0; mi < 4; ++mi) {
        int rb = m0 + wr + mi * 16 + quad * 4;
#pragma unroll
        for (int ni = 0; ni < 4; ++ni) {
            int col = n0 + wc + ni * 16 + lrow;
#pragma unroll
            for (int r = 0; r < 4; ++r) {
                int row = rb + r;
                if (row < NN) {
                    float v = acc[mi][ni][r];
                    if (col < HD) ft[row * HD + col] = f2bf(v);
                    else outf[row * HD + (col - HD)] = v;  // residual init of d_out
                }
            }
        }
    }
}

// ---------------- el/er: per-node attention dots ----------------
__global__ __launch_bounds__(256) void attn_dot_kernel(const u16* __restrict__ ft,
                                                       const void* __restrict__ al,
                                                       const void* __restrict__ ar,
                                                       float* __restrict__ el,
                                                       float* __restrict__ er,
                                                       const int* __restrict__ flags) {
    int node = blockIdx.x * 4 + (threadIdx.x >> 6);
    int lane = threadIdx.x & 63;
    if (node >= NN) return;
    const int alf32 = flags[3];
    const int arf32 = flags[4];
    const u16* f = ft + node * HD;
#pragma unroll
    for (int h = 0; h < HH; ++h) {
        int i = h * 64 + lane;
        float wl = alf32 ? ((const float*)al)[i] : bf2f(((const u16*)al)[i]);
        float wr_ = arf32 ? ((const float*)ar)[i] : bf2f(((const u16*)ar)[i]);
        float x = bf2f(f[i]);
        float vl = x * wl;
        float vr = x * wr_;
#pragma unroll
        for (int off = 32; off > 0; off >>= 1) {
            vl += __shfl_down(vl, off);
            vr += __shfl_down(vr, off);
        }
        if (lane == 0) {
            el[node * HH + h] = vl;
            er[node * HH + h] = vr;
        }
    }
}

// ---- aggregate (gather): one wave per dst node; softmax + weighted sum + residual ----
// lane holds out elements [lane*8, lane*8+8) -> all belong to head = lane>>3.
__global__ __launch_bounds__(256) void aggregate_kernel(const int* __restrict__ rowptr,
                                                        const int* __restrict__ csr_src,
                                                        const u16* __restrict__ ft,
                                                        const float* __restrict__ el,
                                                        const float* __restrict__ er,
                                                        float* __restrict__ outf) {
    int node = blockIdx.x * 4 + (threadIdx.x >> 6);
    if (node >= NN) return;
    int lane = threadIdx.x & 63;
    int head = lane >> 3;
    int beg = rowptr[node], end = rowptr[node + 1];
    float erd = er[node * HH + head];

    // pass 1: segment max of leaky-relu logits (in registers)
    float m = -INFINITY;
    for (int i = beg; i < end; ++i) {
        int s = csr_src[i];
        float v = el[s * HH + head] + erd;
        v = v > 0.0f ? v : 0.2f * v;
        m = fmaxf(m, v);
    }

    // pass 2: exp, denom, weighted feature accumulation
    float acc[8] = {};
    float sden = 0.0f;
    for (int i = beg; i < end; ++i) {
        int s = csr_src[i];
        float v = el[s * HH + head] + erd;
        v = v > 0.0f ? v : 0.2f * v;
        float ex = __expf(v - m);
        sden += ex;
        u16x8 f = *(const u16x8*)(ft + s * HD + lane * 8);
#pragma unroll
        for (int j = 0; j < 8; ++j) acc[j] += bf2f(f[j]) * ex;
    }

    float inv = 1.0f / fmaxf(sden, 1e-9f);
    float* op = outf + node * HD + lane * 8;
    f32x4 r0 = *(const f32x4*)op;
    f32x4 r1 = *(const f32x4*)(op + 4);
    f32x4 o0, o1;
#pragma unroll
    for (int j = 0; j < 4; ++j) {
        o0[j] = acc[j] * inv + r0[j];
        o1[j] = acc[4 + j] * inv + r1[j];
    }
    *(f32x4*)op = o0;
    *(f32x4*)(op + 4) = o1;
}

extern "C" void kernel_launch(void* const* d_in, const int* in_sizes, int n_in,
                              void* d_out, int out_size, void* d_ws, size_t ws_size,
                              hipStream_t stream) {
    const void* feat   = d_in[0];
    const int*  src    = (const int*)d_in[1];
    const int*  dst    = (const int*)d_in[2];
    const void* W_fc   = d_in[3];
    const void* W_res  = d_in[4];
    const void* attn_l = d_in[5];
    const void* attn_r = d_in[6];
    float* outf = (float*)d_out;

    char* ws = (char*)d_ws;
    int*   flags   = (int*)(ws);                //        256 B [feat,wfc,wres,al,ar]
    u16*   Wt      = (u16*)(ws + 256);          //  1,048,576 B [1024][512] bf16
    u16*   ft      = (u16*)(ws + 1048832);      // 51,200,000 B [N][512] bf16
    float* el      = (float*)(ws + 52248832);   //  1,600,000 B [N][8]
    float* er      = (float*)(ws + 53848832);   //  1,600,000 B
    int*   deg     = (int*)(ws + 55448832);     //    200,000 B
    int*   rowptr  = (int*)(ws + 55648832);     //    200,064 B (NN+1)
    int*   cursor  = (int*)(ws + 55848896);     //    200,000 B
    int*   csr_src = (int*)(ws + 56048896);     //  3,200,000 B  (end ~59.2 MB)

    sniff5_kernel<<<5, 256, 0, stream>>>((const u16*)feat, (const u16*)W_fc,
                                         (const u16*)W_res, (const u16*)attn_l,
                                         (const u16*)attn_r, flags);
    transpose_kernel<<<64, 256, 0, stream>>>(W_fc, Wt, flags + 1);
    transpose_kernel<<<64, 256, 0, stream>>>(W_res, Wt + 512 * 512, flags + 2);

    zero_deg_kernel<<<(NN + 255) / 256, 256, 0, stream>>>(deg);
    count_kernel<<<(EE + 255) / 256, 256, 0, stream>>>(dst, deg);
    scan_kernel<<<1, 1024, 0, stream>>>(deg, rowptr, cursor);
    scatter_kernel<<<(EE + 255) / 256, 256, 0, stream>>>(src, dst, cursor, csr_src);

    dim3 gg((NN + TM - 1) / TM, NTOT / TN);
    gemm_kernel<<<gg, 256, 0, stream>>>(feat, Wt, ft, outf, flags + 0);

    attn_dot_kernel<<<(NN + 3) / 4, 256, 0, stream>>>(ft, attn_l, attn_r, el, er, flags);
    aggregate_kernel<<<(NN + 3) / 4, 256, 0, stream>>>(rowptr, csr_src, ft, el, er, outf);
}

// Round 5
// 722.510 us; speedup vs baseline: 2.3896x; 1.0644x over previous
//
#include <hip/hip_runtime.h>
#include <hip/hip_bf16.h>

#define NN 50000
#define EE 800000
#define INF 512
#define HH 8
#define DD 64
#define HD 512
#define NTOT 1024   // fused GEMM output cols: [ft | res]

typedef unsigned short u16;
typedef u16 u16x8 __attribute__((ext_vector_type(8)));
typedef __bf16 bf16x8 __attribute__((ext_vector_type(8)));
typedef float f32x4 __attribute__((ext_vector_type(4)));

__device__ __forceinline__ float bf2f(u16 u) {
    return __uint_as_float(((unsigned)u) << 16);
}
__device__ __forceinline__ u16 f2bf(float f) {
    __hip_bfloat16 h = __float2bfloat16(f);
    return *reinterpret_cast<u16*>(&h);
}

// -------- per-input dtype sniff: flags[i]=1 if input i is f32, 0 if bf16 --------
__global__ __launch_bounds__(256) void sniff5_kernel(const u16* __restrict__ p0,
                                                     const u16* __restrict__ p1,
                                                     const u16* __restrict__ p2,
                                                     const u16* __restrict__ p3,
                                                     const u16* __restrict__ p4,
                                                     int* __restrict__ flags) {
    const u16* ps[5] = {p0, p1, p2, p3, p4};
    const u16* p = ps[blockIdx.x];
    __shared__ int bad;
    if (threadIdx.x == 0) bad = 0;
    __syncthreads();
    float v = fabsf(bf2f(p[2 * threadIdx.x]));
    if (!(v < 1e4f)) atomicAdd(&bad, 1);  // catches huge / inf / NaN
    __syncthreads();
    if (threadIdx.x == 0) flags[blockIdx.x] = (bad >= 8) ? 1 : 0;
}

// ---------------- W transpose (+ dtype convert): Wt[col][k] = W[k][col], 512x512 ----------------
__global__ __launch_bounds__(256) void transpose_kernel(const void* __restrict__ in,
                                                        u16* __restrict__ out,
                                                        const int* __restrict__ flag) {
    __shared__ u16 tile[64][65];
    const int isf32 = *flag;
    int tr = (blockIdx.x & 7) * 64;   // k tile
    int tc = (blockIdx.x >> 3) * 64;  // col tile
    for (int idx = threadIdx.x; idx < 64 * 64; idx += 256) {
        int r = idx >> 6, c = idx & 63;
        int g = (tr + r) * 512 + tc + c;
        tile[r][c] = isf32 ? f2bf(((const float*)in)[g]) : ((const u16*)in)[g];
    }
    __syncthreads();
    for (int idx = threadIdx.x; idx < 64 * 64; idx += 256) {
        int r = idx >> 6, c = idx & 63;
        out[(tc + r) * 512 + tr + c] = tile[c][r];
    }
}

// ---------------- CSR build: deg zero -> count -> scan -> scatter ----------------
__global__ void zero_deg_kernel(int* __restrict__ deg) {
    int t = blockIdx.x * 256 + threadIdx.x;
    if (t < NN) deg[t] = 0;
}

__global__ void count_kernel(const int* __restrict__ dst, int* __restrict__ deg) {
    int e = blockIdx.x * 256 + threadIdx.x;
    if (e < EE) atomicAdd(&deg[dst[e]], 1);
}

#define SCAN_CH 49  // 1024 * 49 = 50176 >= NN
__global__ __launch_bounds__(1024) void scan_kernel(const int* __restrict__ deg,
                                                    int* __restrict__ rowptr,
                                                    int* __restrict__ cursor) {
    __shared__ int sums[1024];
    int t = threadIdx.x;
    int base = t * SCAN_CH;
    int s = 0;
    for (int k = 0; k < SCAN_CH; ++k) {
        int i = base + k;
        if (i < NN) s += deg[i];
    }
    sums[t] = s;
    __syncthreads();
    // Hillis-Steele inclusive scan
    for (int off = 1; off < 1024; off <<= 1) {
        int v = (t >= off) ? sums[t - off] : 0;
        __syncthreads();
        sums[t] += v;
        __syncthreads();
    }
    int run = (t == 0) ? 0 : sums[t - 1];
    for (int k = 0; k < SCAN_CH; ++k) {
        int i = base + k;
        if (i < NN) {
            rowptr[i] = run;
            cursor[i] = run;
            run += deg[i];
        }
    }
    if (t == 0) rowptr[NN] = EE;
}

__global__ void scatter_kernel(const int* __restrict__ src, const int* __restrict__ dst,
                               int* __restrict__ cursor, int* __restrict__ csr_src) {
    int e = blockIdx.x * 256 + threadIdx.x;
    if (e < EE) {
        int p = atomicAdd(&cursor[dst[e]], 1);
        csr_src[p] = src[e];
    }
}

// ---- fused GEMM: [N,512] @ [512,1024] -> ft (bf16) | residual -> out (f32) ----
// 1-D grid, m = bid>>3, n = bid&7: the 8 n-blocks sharing an A-tile are
// temporally adjacent -> A fetched once into LLC (406 MB -> ~110 MB fetch).
#define TM 128
#define TN 128
#define BK 32
#define LDK 40  // padded LDS k-stride (16B-aligned rows, conflicts acceptable)

__global__ __launch_bounds__(256) void gemm_kernel(const void* __restrict__ A,
                                                   const u16* __restrict__ Wt,
                                                   u16* __restrict__ ft,
                                                   float* __restrict__ outf,
                                                   const int* __restrict__ flag) {
    __shared__ u16 As[TM * LDK];
    __shared__ u16 Bs[TN * LDK];
    const int isf32 = *flag;
    const int bid = blockIdx.x;
    const int m0 = (bid >> 3) * TM;
    const int n0 = (bid & 7) * TN;
    const int tid = threadIdx.x;
    const int lane = tid & 63;
    const int wave = tid >> 6;
    const int wr = (wave >> 1) * 64;
    const int wc = (wave & 1) * 64;
    const int lrow = lane & 15;
    const int quad = lane >> 4;

    f32x4 acc[4][4] = {};

    for (int k0 = 0; k0 < INF; k0 += BK) {
        __syncthreads();
#pragma unroll
        for (int it = 0; it < 2; ++it) {
            int chunk = tid + it * 256;
            int r = chunk >> 2;
            int c = (chunk & 3) * 8;
            int gr = m0 + r;
            u16x8 av = {0, 0, 0, 0, 0, 0, 0, 0};
            if (gr < NN) {
                if (isf32) {
                    const f32x4* ap = (const f32x4*)((const float*)A + gr * INF + k0 + c);
                    f32x4 f0 = ap[0], f1 = ap[1];
#pragma unroll
                    for (int j = 0; j < 4; ++j) { av[j] = f2bf(f0[j]); av[4 + j] = f2bf(f1[j]); }
                } else {
                    av = *(const u16x8*)((const u16*)A + gr * INF + k0 + c);
                }
            }
            *(u16x8*)(As + r * LDK + c) = av;
            *(u16x8*)(Bs + r * LDK + c) = *(const u16x8*)(Wt + (n0 + r) * INF + k0 + c);
        }
        __syncthreads();

        bf16x8 af[4], bfr[4];
#pragma unroll
        for (int mi = 0; mi < 4; ++mi)
            af[mi] = *(const bf16x8*)(As + (wr + mi * 16 + lrow) * LDK + quad * 8);
#pragma unroll
        for (int ni = 0; ni < 4; ++ni)
            bfr[ni] = *(const bf16x8*)(Bs + (wc + ni * 16 + lrow) * LDK + quad * 8);
#pragma unroll
        for (int mi = 0; mi < 4; ++mi)
#pragma unroll
            for (int ni = 0; ni < 4; ++ni)
                acc[mi][ni] = __builtin_amdgcn_mfma_f32_16x16x32_bf16(af[mi], bfr[ni],
                                                                      acc[mi][ni], 0, 0, 0);
    }

    // epilogue: C layout col=lane&15, row=quad*4+reg (m89/m91-verified)
#pragma unroll
    for (int mi = 0; mi < 4; ++mi) {
        int rb = m0 + wr + mi * 16 + quad * 4;
#pragma unroll
        for (int ni = 0; ni < 4; ++ni) {
            int col = n0 + wc + ni * 16 + lrow;
#pragma unroll
            for (int r = 0; r < 4; ++r) {
                int row = rb + r;
                if (row < NN) {
                    float v = acc[mi][ni][r];
                    if (col < HD) ft[row * HD + col] = f2bf(v);
                    else outf[row * HD + (col - HD)] = v;  // residual init of d_out
                }
            }
        }
    }
}

// ---------------- el/er: vectorized attention dots, one wave per node ----------------
// lane owns 8 contiguous elems (16B) of head = lane>>3; 3 shfl_xor rounds reduce
// within each 8-lane head group.
__global__ __launch_bounds__(256) void attn_dot_kernel(const u16* __restrict__ ft,
                                                       const void* __restrict__ al,
                                                       const void* __restrict__ ar,
                                                       float* __restrict__ el,
                                                       float* __restrict__ er,
                                                       const int* __restrict__ flags) {
    int node = blockIdx.x * 4 + (threadIdx.x >> 6);
    if (node >= NN) return;
    int lane = threadIdx.x & 63;
    int off = lane * 8;

    float wl[8], wr_[8];
    if (flags[3]) {
        f32x4 a0 = *(const f32x4*)((const float*)al + off);
        f32x4 a1 = *(const f32x4*)((const float*)al + off + 4);
#pragma unroll
        for (int j = 0; j < 4; ++j) { wl[j] = a0[j]; wl[4 + j] = a1[j]; }
    } else {
        u16x8 a = *(const u16x8*)((const u16*)al + off);
#pragma unroll
        for (int j = 0; j < 8; ++j) wl[j] = bf2f(a[j]);
    }
    if (flags[4]) {
        f32x4 a0 = *(const f32x4*)((const float*)ar + off);
        f32x4 a1 = *(const f32x4*)((const float*)ar + off + 4);
#pragma unroll
        for (int j = 0; j < 4; ++j) { wr_[j] = a0[j]; wr_[4 + j] = a1[j]; }
    } else {
        u16x8 a = *(const u16x8*)((const u16*)ar + off);
#pragma unroll
        for (int j = 0; j < 8; ++j) wr_[j] = bf2f(a[j]);
    }

    u16x8 f = *(const u16x8*)(ft + node * HD + off);
    float vl = 0.0f, vr = 0.0f;
#pragma unroll
    for (int j = 0; j < 8; ++j) {
        float x = bf2f(f[j]);
        vl += x * wl[j];
        vr += x * wr_[j];
    }
#pragma unroll
    for (int msk = 1; msk < 8; msk <<= 1) {
        vl += __shfl_xor(vl, msk);
        vr += __shfl_xor(vr, msk);
    }
    if ((lane & 7) == 0) {
        el[node * HH + (lane >> 3)] = vl;
        er[node * HH + (lane >> 3)] = vr;
    }
}

// ---- aggregate (gather): one wave per dst node; online softmax + weighted sum ----
// lane holds out elements [lane*8, lane*8+8) -> all belong to head = lane>>3.
// Software-pipelined: next edge's csr/el/ft loads issued before current compute.
__global__ __launch_bounds__(256) void aggregate_kernel(const int* __restrict__ rowptr,
                                                        const int* __restrict__ csr_src,
                                                        const u16* __restrict__ ft,
                                                        const float* __restrict__ el,
                                                        const float* __restrict__ er,
                                                        float* __restrict__ outf) {
    int node = blockIdx.x * 4 + (threadIdx.x >> 6);
    if (node >= NN) return;
    int lane = threadIdx.x & 63;
    int head = lane >> 3;
    int beg = rowptr[node], end = rowptr[node + 1];
    float erd = er[node * HH + head];

    float m = -INFINITY;
    float sden = 0.0f;
    float acc[8] = {};

    float el_n = 0.0f;
    u16x8 f_n = {};
    if (beg < end) {
        int s0 = csr_src[beg];
        el_n = el[s0 * HH + head];
        f_n = *(const u16x8*)(ft + s0 * HD + lane * 8);
    }
    for (int i = beg; i < end; ++i) {
        float elv = el_n;
        u16x8 f = f_n;
        if (i + 1 < end) {  // prefetch next edge
            int s2 = csr_src[i + 1];
            el_n = el[s2 * HH + head];
            f_n = *(const u16x8*)(ft + s2 * HD + lane * 8);
        }
        float v = elv + erd;
        v = v > 0.0f ? v : 0.2f * v;  // LeakyReLU
        float nm = fmaxf(m, v);
        float scale = __expf(m - nm);  // 0 on first iter (m=-inf), 1 if max unchanged
        float ex = __expf(v - nm);
        m = nm;
        sden = sden * scale + ex;
#pragma unroll
        for (int j = 0; j < 8; ++j) acc[j] = acc[j] * scale + bf2f(f[j]) * ex;
    }

    float inv = 1.0f / fmaxf(sden, 1e-9f);
    float* op = outf + node * HD + lane * 8;
    f32x4 r0 = *(const f32x4*)op;
    f32x4 r1 = *(const f32x4*)(op + 4);
    f32x4 o0, o1;
#pragma unroll
    for (int j = 0; j < 4; ++j) {
        o0[j] = acc[j] * inv + r0[j];
        o1[j] = acc[4 + j] * inv + r1[j];
    }
    *(f32x4*)op = o0;
    *(f32x4*)(op + 4) = o1;
}

extern "C" void kernel_launch(void* const* d_in, const int* in_sizes, int n_in,
                              void* d_out, int out_size, void* d_ws, size_t ws_size,
                              hipStream_t stream) {
    const void* feat   = d_in[0];
    const int*  src    = (const int*)d_in[1];
    const int*  dst    = (const int*)d_in[2];
    const void* W_fc   = d_in[3];
    const void* W_res  = d_in[4];
    const void* attn_l = d_in[5];
    const void* attn_r = d_in[6];
    float* outf = (float*)d_out;

    char* ws = (char*)d_ws;
    int*   flags   = (int*)(ws);                //        256 B [feat,wfc,wres,al,ar]
    u16*   Wt      = (u16*)(ws + 256);          //  1,048,576 B [1024][512] bf16
    u16*   ft      = (u16*)(ws + 1048832);      // 51,200,000 B [N][512] bf16
    float* el      = (float*)(ws + 52248832);   //  1,600,000 B [N][8]
    float* er      = (float*)(ws + 53848832);   //  1,600,000 B
    int*   deg     = (int*)(ws + 55448832);     //    200,000 B
    int*   rowptr  = (int*)(ws + 55648832);     //    200,064 B (NN+1)
    int*   cursor  = (int*)(ws + 55848896);     //    200,000 B
    int*   csr_src = (int*)(ws + 56048896);     //  3,200,000 B  (end ~59.2 MB)

    sniff5_kernel<<<5, 256, 0, stream>>>((const u16*)feat, (const u16*)W_fc,
                                         (const u16*)W_res, (const u16*)attn_l,
                                         (const u16*)attn_r, flags);
    transpose_kernel<<<64, 256, 0, stream>>>(W_fc, Wt, flags + 1);
    transpose_kernel<<<64, 256, 0, stream>>>(W_res, Wt + 512 * 512, flags + 2);

    zero_deg_kernel<<<(NN + 255) / 256, 256, 0, stream>>>(deg);
    count_kernel<<<(EE + 255) / 256, 256, 0, stream>>>(dst, deg);
    scan_kernel<<<1, 1024, 0, stream>>>(deg, rowptr, cursor);
    scatter_kernel<<<(EE + 255) / 256, 256, 0, stream>>>(src, dst, cursor, csr_src);

    int nmblk = (NN + TM - 1) / TM;  // 391
    gemm_kernel<<<nmblk * 8, 256, 0, stream>>>(feat, Wt, ft, outf, flags + 0);

    attn_dot_kernel<<<(NN + 3) / 4, 256, 0, stream>>>(ft, attn_l, attn_r, el, er, flags);
    aggregate_kernel<<<(NN + 3) / 4, 256, 0, stream>>>(rowptr, csr_src, ft, el, er, outf);
}